// Round 7
// baseline (4422.599 us; speedup 1.0000x reference)
//
#include <hip/hip_runtime.h>
#include <cstdint>
#include <cstddef>

#define HDIM 2048
#define NCLS 11
#define NBLK 256
#define NTHR 256
#define CHUNK 256               // h-columns per lane (weights in VGPR/AGPR)
#define CPAD  260               // padded chunk stride in LDS floats

// d_ws: pairs[2][HDIM] of u64 {gen:u32 | h:f32} (32 KiB), memset each launch.
// ALL cross-block traffic = relaxed agent-scope atomics on these u64 pairs.
// Data+tag are one atom -> zero fences, zero ordering ops in the loop
// (R6 proved fences cost ~15 us/step in L2-invalidate side effects).

__device__ __forceinline__ float waveReduceSum(float v) {
#pragma unroll
    for (int off = 32; off > 0; off >>= 1) v += __shfl_xor(v, off, 64);
    return v;
}

// Weight-stationary persistent LSTM, single-atom {h,gen} exchange.
// Block b owns h[b*8..b*8+8). Wave w owns elements {b*8+2w, b*8+2w+1}, all 4
// gates: lane (rl=lane>>3, cc=lane&7) computes row gate(rl&3) of element
// eloc(rl>>2), columns [cc*256, cc*256+256) held in registers.
__global__ void __launch_bounds__(NTHR, 1) lstm_persistent(
    const float* __restrict__ x0,
    const float* __restrict__ Wih,
    const float* __restrict__ Whh,
    const float* __restrict__ bih,
    const float* __restrict__ bhh,
    const float* __restrict__ Wout,
    const float* __restrict__ bout,
    const int* __restrict__ stepsp,
    float* __restrict__ out,
    unsigned long long* __restrict__ pairs0,
    unsigned long long* __restrict__ pairs1)
{
    const int tid  = threadIdx.x;
    const int wave = tid >> 6;
    const int lane = tid & 63;
    const int rl   = lane >> 3;         // 0..7
    const int cc   = lane & 7;          // column chunk
    const int gate = rl & 3;            // i,f,g,o
    const int eloc = rl >> 2;           // 0..1 within wave
    const int bid  = blockIdx.x;
    const int jb   = bid * 8;
    const int elem = jb + 2 * wave + eloc;   // h element this lane serves

    __shared__ float hlds[2][8 * CPAD];

    const int row = gate * HDIM + elem;
    const size_t sbase = (size_t)row * HDIM + (size_t)cc * CHUNK;

    // prefill: w = W_ih slice (step 0 uses W_ih alone since h0 = 0)
    float w[CHUNK];
#pragma unroll
    for (int jj = 0; jj < 64; ++jj) {
        float4 v = *(const float4*)(Wih + sbase + (size_t)jj * 4);
        w[4 * jj + 0] = v.x; w[4 * jj + 1] = v.y;
        w[4 * jj + 2] = v.z; w[4 * jj + 3] = v.w;
    }
    const float bsum = bih[row] + bhh[row];
    float creg = 0.0f, hreg = 0.0f;

    const int steps = stepsp[0];
    const int e0   = tid * 8;                              // elems this thread stages
    const int soff = (tid >> 5) * CPAD + (tid & 31) * 8;   // LDS addr (16B aligned)

    for (int t = 0; t < steps; ++t) {
        const int p = t & 1;
        if (t == 0) {
            float4 a = *(const float4*)(x0 + e0);
            float4 b = *(const float4*)(x0 + e0 + 4);
            *(float4*)&hlds[0][soff]     = a;
            *(float4*)&hlds[0][soff + 4] = b;
        } else {
            const unsigned long long* pp = (p ? pairs1 : pairs0) + e0;
            unsigned long long pv[8];
            for (;;) {
                bool ready = true;
#pragma unroll
                for (int i = 0; i < 8; ++i) {
                    pv[i] = __hip_atomic_load(pp + i, __ATOMIC_RELAXED,
                                              __HIP_MEMORY_SCOPE_AGENT);
                    ready &= ((unsigned)(pv[i] >> 32) == (unsigned)t);
                }
                if (ready) break;
                __builtin_amdgcn_s_sleep(1);
            }
            float4 a, b;
            a.x = __uint_as_float((unsigned)pv[0]);
            a.y = __uint_as_float((unsigned)pv[1]);
            a.z = __uint_as_float((unsigned)pv[2]);
            a.w = __uint_as_float((unsigned)pv[3]);
            b.x = __uint_as_float((unsigned)pv[4]);
            b.y = __uint_as_float((unsigned)pv[5]);
            b.z = __uint_as_float((unsigned)pv[6]);
            b.w = __uint_as_float((unsigned)pv[7]);
            *(float4*)&hlds[p][soff]     = a;
            *(float4*)&hlds[p][soff + 4] = b;
        }
        __syncthreads();     // sole per-step barrier (hlds double-buffered)

        // dot: 256 register weights x LDS-broadcast h chunk
        const float* hc = &hlds[p][cc * CPAD];
        float ax = 0.f, ay = 0.f, az = 0.f, aw = 0.f;
#pragma unroll
        for (int jj = 0; jj < 64; ++jj) {
            float4 hv = *(const float4*)(hc + jj * 4);
            ax += w[4 * jj + 0] * hv.x;
            ay += w[4 * jj + 1] * hv.y;
            az += w[4 * jj + 2] * hv.z;
            aw += w[4 * jj + 3] * hv.w;
        }
        float part = (ax + ay) + (az + aw);
        part += __shfl_xor(part, 1, 64);
        part += __shfl_xor(part, 2, 64);
        part += __shfl_xor(part, 4, 64);        // all 8 lanes: row total
        part += bsum;

        // gather the 4 gate rows of this lane's element (wave-local)
        const int sb = (lane & 0x20) | (lane & 7);
        float gi = __shfl(part, sb + 0,  64);
        float gf = __shfl(part, sb + 8,  64);
        float gg = __shfl(part, sb + 16, 64);
        float go = __shfl(part, sb + 24, 64);

        float si = 1.0f / (1.0f + expf(-gi));
        float sf = 1.0f / (1.0f + expf(-gf));
        float tg = tanhf(gg);
        float so = 1.0f / (1.0f + expf(-go));
        creg = sf * creg + si * tg;             // consistent across the 32 lanes
        hreg = so * tanhf(creg);

        if ((lane & 31) == 0) {                 // lanes 0,32: publish {h, gen}
            unsigned long long pk =
                ((unsigned long long)(unsigned)(t + 1) << 32) |
                (unsigned long long)__float_as_uint(hreg);
            __hip_atomic_store((((t + 1) & 1) ? pairs1 : pairs0) + elem, pk,
                               __ATOMIC_RELAXED, __HIP_MEMORY_SCOPE_AGENT);
        }

        if (t == 0) {
            // switch weights to Wc = W_ih + W_hh for steps >= 1
#pragma unroll
            for (int jj = 0; jj < 64; ++jj) {
                float4 v = *(const float4*)(Whh + sbase + (size_t)jj * 4);
                w[4 * jj + 0] += v.x; w[4 * jj + 1] += v.y;
                w[4 * jj + 2] += v.z; w[4 * jj + 3] += v.w;
            }
        }
    }

    // final h and c straight from registers (disjoint across blocks/waves)
    if ((lane & 31) == 0) {
        out[NCLS + elem]        = hreg;
        out[NCLS + HDIM + elem] = creg;
    }

    // block 0: gather final h (gen == steps), classifier head
    if (bid == 0) {
        __syncthreads();        // all waves past the loop before hlds reuse
        const unsigned long long* pp =
            ((steps & 1) ? pairs1 : pairs0) + e0;
        unsigned long long pv[8];
        for (;;) {
            bool ready = true;
#pragma unroll
            for (int i = 0; i < 8; ++i) {
                pv[i] = __hip_atomic_load(pp + i, __ATOMIC_RELAXED,
                                          __HIP_MEMORY_SCOPE_AGENT);
                ready &= ((unsigned)(pv[i] >> 32) == (unsigned)steps);
            }
            if (ready) break;
            __builtin_amdgcn_s_sleep(1);
        }
#pragma unroll
        for (int i = 0; i < 8; ++i)
            hlds[0][soff + i] = __uint_as_float((unsigned)pv[i]);
        __syncthreads();

        __shared__ float lsm[NCLS];
        float hr[8][4];
#pragma unroll
        for (int k = 0; k < 8; ++k)
#pragma unroll
            for (int c = 0; c < 4; ++c)
                hr[k][c] = hlds[0][k * CPAD + lane * 4 + c];
        for (int r = wave; r < NCLS; r += 4) {
            const float4* w4 = (const float4*)(Wout + (size_t)r * HDIM);
            float sx = 0.f, sy = 0.f, sz = 0.f, sw4 = 0.f;
#pragma unroll
            for (int k = 0; k < 8; ++k) {
                float4 wv = w4[k * 64 + lane];
                sx  += wv.x * hr[k][0];
                sy  += wv.y * hr[k][1];
                sz  += wv.z * hr[k][2];
                sw4 += wv.w * hr[k][3];
            }
            float s = waveReduceSum((sx + sy) + (sz + sw4));
            if (lane == 0) lsm[r] = s + bout[r];
        }
        __syncthreads();
        if (tid == 0) {
            float m = lsm[0];
            for (int r = 1; r < NCLS; ++r) m = fmaxf(m, lsm[r]);
            float ex[NCLS];
            float den = 0.0f;
            for (int r = 0; r < NCLS; ++r) { ex[r] = expf(lsm[r] - m); den += ex[r]; }
            float inv = 1.0f / den;
            for (int r = 0; r < NCLS; ++r) out[r] = ex[r] * inv;
        }
    }
}

extern "C" void kernel_launch(void* const* d_in, const int* in_sizes, int n_in,
                              void* d_out, int out_size, void* d_ws, size_t ws_size,
                              hipStream_t stream) {
    const float* x0    = (const float*)d_in[0];   // row 0 of inputs
    const float* Wih   = (const float*)d_in[1];
    const float* Whh   = (const float*)d_in[2];
    const float* bih   = (const float*)d_in[3];
    const float* bhh   = (const float*)d_in[4];
    const float* Wout  = (const float*)d_in[5];
    const float* bout  = (const float*)d_in[6];
    const int*   steps = (const int*)d_in[7];
    float* out = (float*)d_out;

    unsigned long long* pairs0 = (unsigned long long*)d_ws;
    unsigned long long* pairs1 = pairs0 + HDIM;

    // zero both pair buffers each launch (gen=0 < any step; deterministic)
    hipMemsetAsync(d_ws, 0, (size_t)2 * HDIM * sizeof(unsigned long long),
                   stream);

    lstm_persistent<<<dim3(NBLK), dim3(NTHR), 0, stream>>>(
        x0, Wih, Whh, bih, bhh, Wout, bout, steps, out, pairs0, pairs1);
}

// Round 8
// 4415.699 us; speedup vs baseline: 1.0016x; 1.0016x over previous
//
#include <hip/hip_runtime.h>
#include <cstdint>
#include <cstddef>

#define HDIM 2048
#define NCLS 11
#define NBLK 256
#define NTHR 256
#define CHUNK 256               // h-columns per lane (weights in VGPR/AGPR)
#define CPAD  260               // padded chunk stride in LDS floats

// d_ws: pairs[2][HDIM] of u64 {gen:u32 | h:f32}, PERMUTED layout:
//   elem e lives at s-index (e&7)*256 + (e>>3)
// so consumer thread tid's 8 pairs are {i*256 + tid} -> coalesced loads.
// ALL cross-block traffic = relaxed agent-scope atomics; data+tag are one
// atom -> zero fences (R6: fences cost ~15 us/step in L2-invalidate nukes).
// R7 lesson: poll retry must re-load ONLY not-ready pairs, coalesced.

__device__ __forceinline__ float waveReduceSum(float v) {
#pragma unroll
    for (int off = 32; off > 0; off >>= 1) v += __shfl_xor(v, off, 64);
    return v;
}

// Weight-stationary persistent LSTM, single-atom {h,gen} exchange.
// Block b owns h[b*8..b*8+8). Wave w owns elements {b*8+2w, b*8+2w+1}, all 4
// gates: lane (rl=lane>>3, cc=lane&7) computes row gate(rl&3) of element
// eloc(rl>>2), columns [cc*256, cc*256+256) held in registers.
__global__ void __launch_bounds__(NTHR, 1) lstm_persistent(
    const float* __restrict__ x0,
    const float* __restrict__ Wih,
    const float* __restrict__ Whh,
    const float* __restrict__ bih,
    const float* __restrict__ bhh,
    const float* __restrict__ Wout,
    const float* __restrict__ bout,
    const int* __restrict__ stepsp,
    float* __restrict__ out,
    unsigned long long* __restrict__ pairs0,
    unsigned long long* __restrict__ pairs1)
{
    const int tid  = threadIdx.x;
    const int wave = tid >> 6;
    const int lane = tid & 63;
    const int rl   = lane >> 3;         // 0..7
    const int cc   = lane & 7;          // column chunk
    const int gate = rl & 3;            // i,f,g,o
    const int eloc = rl >> 2;           // 0..1 within wave
    const int bid  = blockIdx.x;
    const int elem = bid * 8 + 2 * wave + eloc;   // h element this lane serves

    __shared__ float hlds[2][8 * CPAD];

    const int row = gate * HDIM + elem;
    const size_t sbase = (size_t)row * HDIM + (size_t)cc * CHUNK;

    // prefill: w = W_ih slice (step 0 uses W_ih alone since h0 = 0)
    float w[CHUNK];
#pragma unroll
    for (int jj = 0; jj < 64; ++jj) {
        float4 v = *(const float4*)(Wih + sbase + (size_t)jj * 4);
        w[4 * jj + 0] = v.x; w[4 * jj + 1] = v.y;
        w[4 * jj + 2] = v.z; w[4 * jj + 3] = v.w;
    }
    const float bsum = bih[row] + bhh[row];
    float creg = 0.0f, hreg = 0.0f;

    const int steps = stepsp[0];
    const int e0   = tid * 8;                              // elems this thread stages
    const int soff = (tid >> 5) * CPAD + (tid & 31) * 8;   // LDS addr (16B aligned)
    // publish s-index for lanes 0/32: (elem&7)*256 + (elem>>3)
    const int pub_si = (2 * wave + (lane >> 5)) * NBLK + bid;

    for (int t = 0; t < steps; ++t) {
        const int p = t & 1;
        if (t == 0) {
            float4 a = *(const float4*)(x0 + e0);
            float4 b = *(const float4*)(x0 + e0 + 4);
            *(float4*)&hlds[0][soff]     = a;
            *(float4*)&hlds[0][soff + 4] = b;
        } else {
            const unsigned long long* pp = (p ? pairs1 : pairs0) + tid;
            unsigned long long pv[8];
            unsigned rdy = 0;
#pragma unroll
            for (int i = 0; i < 8; ++i)
                pv[i] = __hip_atomic_load(pp + i * NBLK, __ATOMIC_RELAXED,
                                          __HIP_MEMORY_SCOPE_AGENT);
            for (;;) {
#pragma unroll
                for (int i = 0; i < 8; ++i)
                    if (!((rdy >> i) & 1u) &&
                        (unsigned)(pv[i] >> 32) == (unsigned)t)
                        rdy |= 1u << i;
                if (rdy == 0xFFu) break;
                __builtin_amdgcn_s_sleep(1);
#pragma unroll
                for (int i = 0; i < 8; ++i)
                    if (!((rdy >> i) & 1u))
                        pv[i] = __hip_atomic_load(pp + i * NBLK, __ATOMIC_RELAXED,
                                                  __HIP_MEMORY_SCOPE_AGENT);
            }
            float4 a, b;
            a.x = __uint_as_float((unsigned)pv[0]);
            a.y = __uint_as_float((unsigned)pv[1]);
            a.z = __uint_as_float((unsigned)pv[2]);
            a.w = __uint_as_float((unsigned)pv[3]);
            b.x = __uint_as_float((unsigned)pv[4]);
            b.y = __uint_as_float((unsigned)pv[5]);
            b.z = __uint_as_float((unsigned)pv[6]);
            b.w = __uint_as_float((unsigned)pv[7]);
            *(float4*)&hlds[p][soff]     = a;
            *(float4*)&hlds[p][soff + 4] = b;
        }
        __syncthreads();     // sole per-step barrier (hlds double-buffered)

        // dot: 256 register weights x LDS-broadcast h chunk
        const float* hc = &hlds[p][cc * CPAD];
        float ax = 0.f, ay = 0.f, az = 0.f, aw = 0.f;
#pragma unroll
        for (int jj = 0; jj < 64; ++jj) {
            float4 hv = *(const float4*)(hc + jj * 4);
            ax += w[4 * jj + 0] * hv.x;
            ay += w[4 * jj + 1] * hv.y;
            az += w[4 * jj + 2] * hv.z;
            aw += w[4 * jj + 3] * hv.w;
        }
        float part = (ax + ay) + (az + aw);
        part += __shfl_xor(part, 1, 64);
        part += __shfl_xor(part, 2, 64);
        part += __shfl_xor(part, 4, 64);        // all 8 lanes: row total
        part += bsum;

        // gather the 4 gate rows of this lane's element (wave-local)
        const int sb = (lane & 0x20) | (lane & 7);
        float gi = __shfl(part, sb + 0,  64);
        float gf = __shfl(part, sb + 8,  64);
        float gg = __shfl(part, sb + 16, 64);
        float go = __shfl(part, sb + 24, 64);

        float si = 1.0f / (1.0f + expf(-gi));
        float sf = 1.0f / (1.0f + expf(-gf));
        float tg = tanhf(gg);
        float so = 1.0f / (1.0f + expf(-go));
        creg = sf * creg + si * tg;             // consistent across the 32 lanes
        hreg = so * tanhf(creg);

        if ((lane & 31) == 0) {                 // lanes 0,32: publish {gen, h}
            unsigned long long pk =
                ((unsigned long long)(unsigned)(t + 1) << 32) |
                (unsigned long long)__float_as_uint(hreg);
            __hip_atomic_store((((t + 1) & 1) ? pairs1 : pairs0) + pub_si, pk,
                               __ATOMIC_RELAXED, __HIP_MEMORY_SCOPE_AGENT);
        }

        if (t == 0) {
            // switch weights to Wc = W_ih + W_hh for steps >= 1
#pragma unroll
            for (int jj = 0; jj < 64; ++jj) {
                float4 v = *(const float4*)(Whh + sbase + (size_t)jj * 4);
                w[4 * jj + 0] += v.x; w[4 * jj + 1] += v.y;
                w[4 * jj + 2] += v.z; w[4 * jj + 3] += v.w;
            }
        }
    }

    // final h and c straight from registers (disjoint across blocks/waves)
    if ((lane & 31) == 0) {
        out[NCLS + elem]        = hreg;
        out[NCLS + HDIM + elem] = creg;
    }

    // block 0: gather final h (gen == steps), classifier head
    if (bid == 0) {
        __syncthreads();        // all waves past the loop before hlds reuse
        const unsigned long long* pp =
            ((steps & 1) ? pairs1 : pairs0) + tid;
        unsigned long long pv[8];
        unsigned rdy = 0;
#pragma unroll
        for (int i = 0; i < 8; ++i)
            pv[i] = __hip_atomic_load(pp + i * NBLK, __ATOMIC_RELAXED,
                                      __HIP_MEMORY_SCOPE_AGENT);
        for (;;) {
#pragma unroll
            for (int i = 0; i < 8; ++i)
                if (!((rdy >> i) & 1u) &&
                    (unsigned)(pv[i] >> 32) == (unsigned)steps)
                    rdy |= 1u << i;
            if (rdy == 0xFFu) break;
            __builtin_amdgcn_s_sleep(1);
#pragma unroll
            for (int i = 0; i < 8; ++i)
                if (!((rdy >> i) & 1u))
                    pv[i] = __hip_atomic_load(pp + i * NBLK, __ATOMIC_RELAXED,
                                              __HIP_MEMORY_SCOPE_AGENT);
        }
#pragma unroll
        for (int i = 0; i < 8; ++i)
            hlds[0][soff + i] = __uint_as_float((unsigned)pv[i]);
        __syncthreads();

        __shared__ float lsm[NCLS];
        float hr[8][4];
#pragma unroll
        for (int k = 0; k < 8; ++k)
#pragma unroll
            for (int c = 0; c < 4; ++c)
                hr[k][c] = hlds[0][k * CPAD + lane * 4 + c];
        for (int r = wave; r < NCLS; r += 4) {
            const float4* w4 = (const float4*)(Wout + (size_t)r * HDIM);
            float sx = 0.f, sy = 0.f, sz = 0.f, sw4 = 0.f;
#pragma unroll
            for (int k = 0; k < 8; ++k) {
                float4 wv = w4[k * 64 + lane];
                sx  += wv.x * hr[k][0];
                sy  += wv.y * hr[k][1];
                sz  += wv.z * hr[k][2];
                sw4 += wv.w * hr[k][3];
            }
            float s = waveReduceSum((sx + sy) + (sz + sw4));
            if (lane == 0) lsm[r] = s + bout[r];
        }
        __syncthreads();
        if (tid == 0) {
            float m = lsm[0];
            for (int r = 1; r < NCLS; ++r) m = fmaxf(m, lsm[r]);
            float ex[NCLS];
            float den = 0.0f;
            for (int r = 0; r < NCLS; ++r) { ex[r] = expf(lsm[r] - m); den += ex[r]; }
            float inv = 1.0f / den;
            for (int r = 0; r < NCLS; ++r) out[r] = ex[r] * inv;
        }
    }
}

extern "C" void kernel_launch(void* const* d_in, const int* in_sizes, int n_in,
                              void* d_out, int out_size, void* d_ws, size_t ws_size,
                              hipStream_t stream) {
    const float* x0    = (const float*)d_in[0];   // row 0 of inputs
    const float* Wih   = (const float*)d_in[1];
    const float* Whh   = (const float*)d_in[2];
    const float* bih   = (const float*)d_in[3];
    const float* bhh   = (const float*)d_in[4];
    const float* Wout  = (const float*)d_in[5];
    const float* bout  = (const float*)d_in[6];
    const int*   steps = (const int*)d_in[7];
    float* out = (float*)d_out;

    unsigned long long* pairs0 = (unsigned long long*)d_ws;
    unsigned long long* pairs1 = pairs0 + HDIM;

    // zero both pair buffers each launch (gen=0 < any step; deterministic)
    hipMemsetAsync(d_ws, 0, (size_t)2 * HDIM * sizeof(unsigned long long),
                   stream);

    lstm_persistent<<<dim3(NBLK), dim3(NTHR), 0, stream>>>(
        x0, Wih, Whh, bih, bhh, Wout, bout, steps, out, pairs0, pairs1);
}

// Round 9
// 3113.107 us; speedup vs baseline: 1.4206x; 1.4184x over previous
//
#include <hip/hip_runtime.h>
#include <cstdint>
#include <cstddef>

#define HDIM 2048
#define NCLS 11
#define NBLK 256
#define NTHR 256
#define CHUNK 256               // h-columns per lane (weights in VGPR/AGPR)
#define CPAD  260               // padded chunk stride in LDS floats

// d_ws:
//   [0, 16KB)        pairs0: u64 {gen:u32 | h:f32}, permuted: elem e at
//                    s-index (e&7)*256 + (e>>3)  (consumer loads coalesced)
//   [16KB, 32KB)     pairs1 (other step parity)
//   [32KB, +512B)    root_gen, replicated on 8 lines 64B apart
// All cross-block traffic = relaxed agent-scope atomics; data+tag one atom;
// ZERO fences (R6: fences cost ~15 us/step in L2-invalidate nukes).
// R7/R8 lesson: detection cost scales with CONCURRENT POLLERS at the IFC,
// not with poll bytes -> aggregate detection in ONE root block, everyone
// else polls a replicated root_gen line (1 line-request per wave per round).

__device__ __forceinline__ float waveReduceSum(float v) {
#pragma unroll
    for (int off = 32; off > 0; off >>= 1) v += __shfl_xor(v, off, 64);
    return v;
}

// Weight-stationary persistent LSTM, root-aggregated readiness.
// Block b owns h[b*8..b*8+8). Wave w owns elements {b*8+2w, b*8+2w+1}, all 4
// gates: lane (rl=lane>>3, cc=lane&7) computes row gate(rl&3) of element
// eloc(rl>>2), columns [cc*256, cc*256+256) held in registers.
__global__ void __launch_bounds__(NTHR, 1) lstm_persistent(
    const float* __restrict__ x0,
    const float* __restrict__ Wih,
    const float* __restrict__ Whh,
    const float* __restrict__ bih,
    const float* __restrict__ bhh,
    const float* __restrict__ Wout,
    const float* __restrict__ bout,
    const int* __restrict__ stepsp,
    float* __restrict__ out,
    unsigned long long* __restrict__ pairs0,
    unsigned long long* __restrict__ pairs1,
    unsigned* __restrict__ rootgen)      // 8 copies, 16 uints apart
{
    const int tid  = threadIdx.x;
    const int wave = tid >> 6;
    const int lane = tid & 63;
    const int rl   = lane >> 3;         // 0..7
    const int cc   = lane & 7;          // column chunk
    const int gate = rl & 3;            // i,f,g,o
    const int eloc = rl >> 2;           // 0..1 within wave
    const int bid  = blockIdx.x;
    const int elem = bid * 8 + 2 * wave + eloc;   // h element this lane serves

    __shared__ float hlds[2][8 * CPAD];

    const int row = gate * HDIM + elem;
    const size_t sbase = (size_t)row * HDIM + (size_t)cc * CHUNK;

    // prefill: w = W_ih slice (step 0 uses W_ih alone since h0 = 0)
    float w[CHUNK];
#pragma unroll
    for (int jj = 0; jj < 64; ++jj) {
        float4 v = *(const float4*)(Wih + sbase + (size_t)jj * 4);
        w[4 * jj + 0] = v.x; w[4 * jj + 1] = v.y;
        w[4 * jj + 2] = v.z; w[4 * jj + 3] = v.w;
    }
    const float bsum = bih[row] + bhh[row];
    float creg = 0.0f, hreg = 0.0f;

    const int steps = stepsp[0];
    const int e0   = tid * 8;                              // elems this thread stages
    const int soff = (tid >> 5) * CPAD + (tid & 31) * 8;   // LDS addr (16B aligned)
    // publish s-index for lanes 0/32: (elem&7)*256 + (elem>>3)
    const int pub_si = (2 * wave + (lane >> 5)) * NBLK + bid;
    // which root_gen replica this wave polls
    unsigned* mygen = rootgen + (((bid << 2) + wave) & 7) * 16;

    for (int t = 0; t < steps; ++t) {
        const int p = t & 1;
        if (t == 0) {
            float4 a = *(const float4*)(x0 + e0);
            float4 b = *(const float4*)(x0 + e0 + 4);
            *(float4*)&hlds[0][soff]     = a;
            *(float4*)&hlds[0][soff + 4] = b;
        } else {
            if (bid != 0) {     // root block already proved readiness via scan
                while (__hip_atomic_load(mygen, __ATOMIC_RELAXED,
                                         __HIP_MEMORY_SCOPE_AGENT) < (unsigned)t)
                    __builtin_amdgcn_s_sleep(1);
                asm volatile("" ::: "memory");   // no load hoisting above spin
            }
            const unsigned long long* pp = (p ? pairs1 : pairs0) + tid;
            unsigned long long pv[8];
#pragma unroll
            for (int i = 0; i < 8; ++i)          // single burst, no retry
                pv[i] = __hip_atomic_load(pp + i * NBLK, __ATOMIC_RELAXED,
                                          __HIP_MEMORY_SCOPE_AGENT);
            float4 a, b;
            a.x = __uint_as_float((unsigned)pv[0]);
            a.y = __uint_as_float((unsigned)pv[1]);
            a.z = __uint_as_float((unsigned)pv[2]);
            a.w = __uint_as_float((unsigned)pv[3]);
            b.x = __uint_as_float((unsigned)pv[4]);
            b.y = __uint_as_float((unsigned)pv[5]);
            b.z = __uint_as_float((unsigned)pv[6]);
            b.w = __uint_as_float((unsigned)pv[7]);
            *(float4*)&hlds[p][soff]     = a;
            *(float4*)&hlds[p][soff + 4] = b;
        }
        __syncthreads();     // stage complete (hlds double-buffered)

        // dot: 256 register weights x LDS-broadcast h chunk
        const float* hc = &hlds[p][cc * CPAD];
        float ax = 0.f, ay = 0.f, az = 0.f, aw = 0.f;
#pragma unroll
        for (int jj = 0; jj < 64; ++jj) {
            float4 hv = *(const float4*)(hc + jj * 4);
            ax += w[4 * jj + 0] * hv.x;
            ay += w[4 * jj + 1] * hv.y;
            az += w[4 * jj + 2] * hv.z;
            aw += w[4 * jj + 3] * hv.w;
        }
        float part = (ax + ay) + (az + aw);
        part += __shfl_xor(part, 1, 64);
        part += __shfl_xor(part, 2, 64);
        part += __shfl_xor(part, 4, 64);        // all 8 lanes: row total
        part += bsum;

        // gather the 4 gate rows of this lane's element (wave-local)
        const int sb = (lane & 0x20) | (lane & 7);
        float gi = __shfl(part, sb + 0,  64);
        float gf = __shfl(part, sb + 8,  64);
        float gg = __shfl(part, sb + 16, 64);
        float go = __shfl(part, sb + 24, 64);

        float si = 1.0f / (1.0f + expf(-gi));
        float sf = 1.0f / (1.0f + expf(-gf));
        float tg = tanhf(gg);
        float so = 1.0f / (1.0f + expf(-go));
        creg = sf * creg + si * tg;             // consistent across the 32 lanes
        hreg = so * tanhf(creg);

        if ((lane & 31) == 0) {                 // lanes 0,32: publish {gen, h}
            unsigned long long pk =
                ((unsigned long long)(unsigned)(t + 1) << 32) |
                (unsigned long long)__float_as_uint(hreg);
            __hip_atomic_store((((t + 1) & 1) ? pairs1 : pairs0) + pub_si, pk,
                               __ATOMIC_RELAXED, __HIP_MEMORY_SCOPE_AGENT);
        }

        if (t == 0) {
            // switch weights to Wc = W_ih + W_hh for steps >= 1
#pragma unroll
            for (int jj = 0; jj < 64; ++jj) {
                float4 v = *(const float4*)(Whh + sbase + (size_t)jj * 4);
                w[4 * jj + 0] += v.x; w[4 * jj + 1] += v.y;
                w[4 * jj + 2] += v.z; w[4 * jj + 3] += v.w;
            }
        }

        // root duties: block 0 scans all pairs of parity (t+1), then
        // broadcasts root_gen = t+1 on 8 replicated lines.
        if (bid == 0) {
            const unsigned long long* sp =
                (((t + 1) & 1) ? pairs1 : pairs0) + tid;
            unsigned long long sv[8];
            unsigned rdy = 0;
#pragma unroll
            for (int i = 0; i < 8; ++i)
                sv[i] = __hip_atomic_load(sp + i * NBLK, __ATOMIC_RELAXED,
                                          __HIP_MEMORY_SCOPE_AGENT);
            for (;;) {
#pragma unroll
                for (int i = 0; i < 8; ++i)
                    if (!((rdy >> i) & 1u) &&
                        (unsigned)(sv[i] >> 32) == (unsigned)(t + 1))
                        rdy |= 1u << i;
                if (rdy == 0xFFu) break;
                __builtin_amdgcn_s_sleep(1);
#pragma unroll
                for (int i = 0; i < 8; ++i)
                    if (!((rdy >> i) & 1u))
                        sv[i] = __hip_atomic_load(sp + i * NBLK,
                                                  __ATOMIC_RELAXED,
                                                  __HIP_MEMORY_SCOPE_AGENT);
            }
            __syncthreads();                    // AND across the 4 scan waves
            if (tid < 8)
                __hip_atomic_store(rootgen + tid * 16, (unsigned)(t + 1),
                                   __ATOMIC_RELAXED, __HIP_MEMORY_SCOPE_AGENT);
        }
    }

    // final h and c straight from registers (disjoint across blocks/waves)
    if ((lane & 31) == 0) {
        out[NCLS + elem]        = hreg;
        out[NCLS + HDIM + elem] = creg;
    }

    // block 0: final scan already proved pairs[steps&1] ready -> direct load
    if (bid == 0) {
        const unsigned long long* pp =
            ((steps & 1) ? pairs1 : pairs0) + tid;
        unsigned long long pv[8];
#pragma unroll
        for (int i = 0; i < 8; ++i)
            pv[i] = __hip_atomic_load(pp + i * NBLK, __ATOMIC_RELAXED,
                                      __HIP_MEMORY_SCOPE_AGENT);
#pragma unroll
        for (int i = 0; i < 8; ++i)
            hlds[0][soff + i] = __uint_as_float((unsigned)pv[i]);
        __syncthreads();

        __shared__ float lsm[NCLS];
        float hr[8][4];
#pragma unroll
        for (int k = 0; k < 8; ++k)
#pragma unroll
            for (int c = 0; c < 4; ++c)
                hr[k][c] = hlds[0][k * CPAD + lane * 4 + c];
        for (int r = wave; r < NCLS; r += 4) {
            const float4* w4 = (const float4*)(Wout + (size_t)r * HDIM);
            float sx = 0.f, sy = 0.f, sz = 0.f, sw4 = 0.f;
#pragma unroll
            for (int k = 0; k < 8; ++k) {
                float4 wv = w4[k * 64 + lane];
                sx  += wv.x * hr[k][0];
                sy  += wv.y * hr[k][1];
                sz  += wv.z * hr[k][2];
                sw4 += wv.w * hr[k][3];
            }
            float s = waveReduceSum((sx + sy) + (sz + sw4));
            if (lane == 0) lsm[r] = s + bout[r];
        }
        __syncthreads();
        if (tid == 0) {
            float m = lsm[0];
            for (int r = 1; r < NCLS; ++r) m = fmaxf(m, lsm[r]);
            float ex[NCLS];
            float den = 0.0f;
            for (int r = 0; r < NCLS; ++r) { ex[r] = expf(lsm[r] - m); den += ex[r]; }
            float inv = 1.0f / den;
            for (int r = 0; r < NCLS; ++r) out[r] = ex[r] * inv;
        }
    }
}

extern "C" void kernel_launch(void* const* d_in, const int* in_sizes, int n_in,
                              void* d_out, int out_size, void* d_ws, size_t ws_size,
                              hipStream_t stream) {
    const float* x0    = (const float*)d_in[0];   // row 0 of inputs
    const float* Wih   = (const float*)d_in[1];
    const float* Whh   = (const float*)d_in[2];
    const float* bih   = (const float*)d_in[3];
    const float* bhh   = (const float*)d_in[4];
    const float* Wout  = (const float*)d_in[5];
    const float* bout  = (const float*)d_in[6];
    const int*   steps = (const int*)d_in[7];
    float* out = (float*)d_out;

    unsigned long long* pairs0 = (unsigned long long*)d_ws;
    unsigned long long* pairs1 = pairs0 + HDIM;
    unsigned* rootgen = (unsigned*)((char*)d_ws + 2 * HDIM * sizeof(unsigned long long));

    // zero pairs (gen=0) + rootgen replicas each launch (graph-replay safe)
    hipMemsetAsync(d_ws, 0,
                   (size_t)2 * HDIM * sizeof(unsigned long long) + 512, stream);

    lstm_persistent<<<dim3(NBLK), dim3(NTHR), 0, stream>>>(
        x0, Wih, Whh, bih, bhh, Wout, bout, steps, out,
        pairs0, pairs1, rootgen);
}